// Round 8
// baseline (140.637 us; speedup 1.0000x reference)
//
#include <hip/hip_runtime.h>
#include <hip/hip_bf16.h>

// ScaledDotProdAttn (no softmax): attn = (q@k^T)/8 ; out = attn@v
// B=32, SQ=SK=2048, D=64, fp32 in/out. d_out = [out] ++ [attn]
// R8 = R7's structure (dual-orientation 32x32x16 QK^T, zero-LDS S path,
//     8 waves = 4 q-groups x 2 key-halves, end O-reduce) with SAFE
//     primitives: __shfl_xor half-swap instead of permlane asm, C-level
//     bf16 packing instead of cvt_pk asm, memcpy type-punning.

typedef __attribute__((ext_vector_type(4)))  float        f32x4;
typedef __attribute__((ext_vector_type(16))) float        f32x16;
typedef __attribute__((ext_vector_type(8)))  short        s16x8;

#define NB    32
#define SQL   2048
#define SKL   2048
#define DD    64
#define QBLK  128
#define KBLK  64
#define NTILES (SKL / KBLK)

// LDS (32 KB):
//  K dbuf [sel][kh][kstep][key32][half16B] ; V dbuf [sel][kh][ps][d64][half16B]
//  (frag reads: 64 lanes -> 1024B contiguous, conflict-free)
//  epilogue: smem reused as 4 x 8KB fp32 O-reduce scratch (per qw)
#define KOFF 0
#define VOFF 16384

__device__ __forceinline__ unsigned short f2bf(float f) {
    union { float f; unsigned u; } x; x.f = f;
    unsigned r = x.u + 0x7FFFu + ((x.u >> 16) & 1u);   // RNE
    return (unsigned short)(r >> 16);
}
// pack two fp32 -> two bf16 (truncation; PV-path only, attn stays fp32)
__device__ __forceinline__ unsigned pkbf(float lo, float hi) {
    union { float f; unsigned u; } a, b; a.f = lo; b.f = hi;
    return (a.u >> 16) | (b.u & 0xFFFF0000u);
}

__global__ __launch_bounds__(512, 4)
void sdpa_fused(const float* __restrict__ qg, const float* __restrict__ kg,
                const float* __restrict__ vg, float* __restrict__ og,
                float* __restrict__ ag) {
    __shared__ __align__(16) char smem[32768];

    const unsigned tid  = threadIdx.x;
    const unsigned wid  = tid >> 6;          // 0..7
    const unsigned lane = tid & 63u;
    const unsigned l31  = lane & 31u;
    const unsigned l5   = lane >> 5;         // 0,1
    const bool     lo   = (l5 == 0);
    const unsigned qw   = wid >> 1;          // 0..3 : q-group (32 rows)
    const unsigned kh   = wid & 1u;          // 0,1  : key-half (32 keys)

    // XCD-aware mapping (R4 win: FETCH 417->43 MB)
    const unsigned xcd = blockIdx.x & 7u;
    const unsigned loc = blockIdx.x >> 3;
    const unsigned b   = xcd * 4u + (loc >> 4);
    const unsigned qt  = loc & 15u;
    const unsigned qbase = qt * QBLK;

    // ---- Q -> fragments (scale folded); serves as both A and B operand ----
    s16x8 qf[4];
    {
        const float* qrow = qg + (size_t)(b * SQL + qbase + qw * 32 + l31) * DD;
        #pragma unroll
        for (int kk = 0; kk < 4; ++kk) {
            f32x4 f0 = *(const f32x4*)(qrow + kk * 16 + l5 * 8);
            f32x4 f1 = *(const f32x4*)(qrow + kk * 16 + l5 * 8 + 4);
            #pragma unroll
            for (int j = 0; j < 4; ++j) {
                qf[kk][j]     = (short)f2bf(f0[j] * 0.125f);
                qf[kk][j + 4] = (short)f2bf(f1[j] * 0.125f);
            }
        }
    }

    f32x16 acc_o0 = {0,0,0,0,0,0,0,0,0,0,0,0,0,0,0,0};
    f32x16 acc_o1 = {0,0,0,0,0,0,0,0,0,0,0,0,0,0,0,0};

    const float* kbat = kg + (size_t)b * SKL * DD;
    const float* vbat = vg + (size_t)b * SKL * DD;

    auto stage = [&](int kt, int sel) {
        const float* ksrc = kbat + (size_t)kt * KBLK * DD;
        const float* vsrc = vbat + (size_t)kt * KBLK * DD;
        // K: thread -> key=tid>>3 (0..63), d0=(tid&7)*8 ; one b128 LDS write
        {
            unsigned key = tid >> 3, d0 = (tid & 7u) * 8;
            f32x4 a0 = *(const f32x4*)(ksrc + key * DD + d0);
            f32x4 a1 = *(const f32x4*)(ksrc + key * DD + d0 + 4);
            s16x8 h;
            #pragma unroll
            for (int j = 0; j < 4; ++j) {
                h[j]     = (short)f2bf(a0[j]);
                h[j + 4] = (short)f2bf(a1[j]);
            }
            *(s16x8*)(smem + KOFF + sel * 8192 + (key >> 5) * 4096 +
                      (d0 >> 4) * 1024 + (key & 31u) * 32 + ((d0 >> 3) & 1u) * 16) = h;
        }
        // V: thread -> key pair (2kp,2kp+1), d0=dq*4 ; four b32 writes
        {
            unsigned kp = tid & 31u, dq = tid >> 5;   // dq 0..15
            unsigned k0 = kp * 2, d0 = dq * 4;
            f32x4 v0 = *(const f32x4*)(vsrc + (size_t)k0 * DD + d0);
            f32x4 v1 = *(const f32x4*)(vsrc + (size_t)(k0 + 1) * DD + d0);
            char* vb = smem + VOFF + sel * 8192 + (kp >> 4) * 4096 +
                       ((kp >> 3) & 1u) * 2048 + ((kp >> 2) & 1u) * 16 + (kp & 3u) * 4;
            #pragma unroll
            for (int j = 0; j < 4; ++j) {
                unsigned pack = (unsigned)f2bf(v0[j]) | ((unsigned)f2bf(v1[j]) << 16);
                *(unsigned*)(vb + (d0 + (unsigned)j) * 32) = pack;
            }
        }
    };

    stage(0, 0);
    __syncthreads();

    // attn base: row q = qbase+qw*32+4*l5 (+crow(r)), col = kh*32+l31 (+kt*64)
    float* const aw = ag + (size_t)(b * SQL + qbase + qw * 32 + 4 * l5) * SKL
                         + kh * 32 + l31;

    for (int kt = 0; kt < NTILES; ++kt) {
        const int sel = kt & 1;
        if (kt + 1 < NTILES) stage(kt + 1, sel ^ 1);

        // ---- dual QK^T: as = S^T (q in lanes), an = S (key in lanes) ----
        const char* ka = smem + KOFF + sel * 8192 + kh * 4096 + l31 * 32 + l5 * 16;
        f32x16 as = {0,0,0,0,0,0,0,0,0,0,0,0,0,0,0,0};
        f32x16 an = {0,0,0,0,0,0,0,0,0,0,0,0,0,0,0,0};
        #pragma unroll
        for (int kk = 0; kk < 4; ++kk) {
            s16x8 kf = *(const s16x8*)(ka + kk * 1024);
            as = __builtin_amdgcn_mfma_f32_32x32x16_bf16(kf, qf[kk], as, 0, 0, 0);
            an = __builtin_amdgcn_mfma_f32_32x32x16_bf16(qf[kk], kf, an, 0, 0, 0);
        }

        // ---- attn stores: fp32 from an, 128B row segments ----
        {
            float* ap = aw + (size_t)kt * KBLK;
            #pragma unroll
            for (int r = 0; r < 16; ++r)
                __builtin_nontemporal_store(an[r],
                    ap + (size_t)((r & 3) + 8 * (r >> 2)) * SKL);
        }

        // ---- S^T -> bf16 PV A-frags in-register (pack + half-lane swap) ----
        unsigned c0 = pkbf(as[0],  as[1]);
        unsigned c1 = pkbf(as[2],  as[3]);
        unsigned c2 = pkbf(as[4],  as[5]);
        unsigned c3 = pkbf(as[6],  as[7]);
        unsigned c4 = pkbf(as[8],  as[9]);
        unsigned c5 = pkbf(as[10], as[11]);
        unsigned c6 = pkbf(as[12], as[13]);
        unsigned c7 = pkbf(as[14], as[15]);
        // half-swap: a<-{lo:a, hi:b_lo}, b<-{lo:a_hi, hi:b}  (lane^32 exchange)
        {
            unsigned t;
            t = __shfl_xor(c0, 32); unsigned u = __shfl_xor(c2, 32);
            c2 = lo ? t : c2;  c0 = lo ? c0 : u;
            t = __shfl_xor(c1, 32); u = __shfl_xor(c3, 32);
            c3 = lo ? t : c3;  c1 = lo ? c1 : u;
            t = __shfl_xor(c4, 32); u = __shfl_xor(c6, 32);
            c6 = lo ? t : c6;  c4 = lo ? c4 : u;
            t = __shfl_xor(c5, 32); u = __shfl_xor(c7, 32);
            c7 = lo ? t : c7;  c5 = lo ? c5 : u;
        }
        s16x8 pa0, pa1;
        {
            unsigned w0[4] = {c0, c1, c2, c3};
            unsigned w1[4] = {c4, c5, c6, c7};
            __builtin_memcpy(&pa0, w0, 16);
            __builtin_memcpy(&pa1, w1, 16);
        }

        // ---- PV: O[32q x 64d] += S[32q x 32k] @ V[32k x 64d] ----
        const char* vbp = smem + VOFF + sel * 8192 + kh * 4096 + l5 * 16;
        {
            s16x8 vf00 = *(const s16x8*)(vbp + 0    + (0 * 32 + l31) * 32);
            s16x8 vf01 = *(const s16x8*)(vbp + 0    + (1 * 32 + l31) * 32);
            s16x8 vf10 = *(const s16x8*)(vbp + 2048 + (0 * 32 + l31) * 32);
            s16x8 vf11 = *(const s16x8*)(vbp + 2048 + (1 * 32 + l31) * 32);
            acc_o0 = __builtin_amdgcn_mfma_f32_32x32x16_bf16(pa0, vf00, acc_o0, 0, 0, 0);
            acc_o1 = __builtin_amdgcn_mfma_f32_32x32x16_bf16(pa0, vf01, acc_o1, 0, 0, 0);
            acc_o0 = __builtin_amdgcn_mfma_f32_32x32x16_bf16(pa1, vf10, acc_o0, 0, 0, 0);
            acc_o1 = __builtin_amdgcn_mfma_f32_32x32x16_bf16(pa1, vf11, acc_o1, 0, 0, 0);
        }

        __syncthreads();   // dbuf flip
    }

    // ---- O reduce across key-half wave pairs, then store ----
    float* red = (float*)smem + qw * 2048;   // [qloc 32][d 64]
    if (kh == 1) {
        #pragma unroll
        for (int r = 0; r < 16; ++r) {
            unsigned qloc = (r & 3) + 8 * (r >> 2) + 4 * l5;
            red[qloc * 64 +      l31] = acc_o0[r];
            red[qloc * 64 + 32 + l31] = acc_o1[r];
        }
    }
    __syncthreads();
    if (kh == 0) {
        float* op = og + (size_t)(b * SQL + qbase + qw * 32) * DD;
        #pragma unroll
        for (int r = 0; r < 16; ++r) {
            unsigned qloc = (r & 3) + 8 * (r >> 2) + 4 * l5;
            float v0 = acc_o0[r] + red[qloc * 64 +      l31];
            float v1 = acc_o1[r] + red[qloc * 64 + 32 + l31];
            __builtin_nontemporal_store(v0, op + (size_t)qloc * DD +      l31);
            __builtin_nontemporal_store(v1, op + (size_t)qloc * DD + 32 + l31);
        }
    }
}

extern "C" void kernel_launch(void* const* d_in, const int* in_sizes, int n_in,
                              void* d_out, int out_size, void* d_ws, size_t ws_size,
                              hipStream_t stream) {
    const float* q = (const float*)d_in[0];
    const float* k = (const float*)d_in[1];
    const float* v = (const float*)d_in[2];
    float* outp  = (float*)d_out;                      // [32][2048][64]
    float* attnp = outp + (size_t)NB * SQL * DD;       // [32][2048][2048]
    sdpa_fused<<<dim3(NB * (SQL / QBLK)), dim3(512), 0, stream>>>(q, k, v, outp, attnp);
}

// Round 9
// 129.008 us; speedup vs baseline: 1.0901x; 1.0901x over previous
//
#include <hip/hip_runtime.h>
#include <hip/hip_bf16.h>

// ScaledDotProdAttn (no softmax): attn = (q@k^T)/8 ; out = attn@v
// B=32, SQ=SK=2048, D=64, fp32 in/out. d_out = [out] ++ [attn]
// R9 = R5 (best, 127.4us) + ONE change: lgkm-only barrier instead of
// __syncthreads(), so the per-tile vmcnt(0) drain of NT attn stores is
// removed (stores retire lazily across tiles). Correctness needs only LDS
// ordering: dbuf staging writes the non-current buffer, S is wave-private.

typedef __attribute__((ext_vector_type(4))) float        f32x4;
typedef __attribute__((ext_vector_type(8))) short        s16x8;
typedef __attribute__((ext_vector_type(2))) unsigned int u32x2;
typedef __attribute__((ext_vector_type(4))) unsigned int u32x4;

#define NB    32
#define SQL   2048
#define SKL   2048
#define DD    64
#define QBLK  128
#define KBLK  64
#define NTILES (SKL / KBLK)

// LDS (48 KB -> 2 blocks/CU with 512-thread blocks = 16 waves/CU):
//   [0    ,16384) K dbuf : 2 x (64 keys x 64 bf16), row stride 128 B
//   [16384,32768) V^T dbuf: 2 x (64 d x 64 keys bf16 packed), stride 128 B
//   [32768,49152) S priv : 8 waves x (16 q x 64 k bf16), stride 128 B
#define KOFF 0
#define VOFF 16384
#define SOFF 32768

__device__ __forceinline__ unsigned short f2bf(float f) {
    union { float f; unsigned u; } x; x.f = f;
    unsigned r = x.u + 0x7FFFu + ((x.u >> 16) & 1u);   // RNE
    return (unsigned short)(r >> 16);
}
// swizzles: XOR into byte-addr bits 4..6 (row stride 128 B everywhere)
__device__ __forceinline__ unsigned swzK(unsigned k) { return (k & 7u) << 4; }
__device__ __forceinline__ unsigned swzV(unsigned d) { return (d & 7u) << 4; }
__device__ __forceinline__ unsigned swzS(unsigned q) { return ((q + (q >> 3)) & 7u) << 4; }

// Workgroup barrier draining LDS only: global (NT attn) stores stay in
// flight; the compiler's counted vmcnt still protects load uses.
__device__ __forceinline__ void bar_lds() {
    asm volatile("s_waitcnt lgkmcnt(0)" ::: "memory");
    __builtin_amdgcn_s_barrier();
    asm volatile("" ::: "memory");
}

__global__ __launch_bounds__(512, 4)
void sdpa_fused(const float* __restrict__ qg, const float* __restrict__ kg,
                const float* __restrict__ vg, float* __restrict__ og,
                float* __restrict__ ag) {
    __shared__ __align__(16) char smem[49152];

    const unsigned tid  = threadIdx.x;
    const unsigned wid  = tid >> 6;          // 0..7
    const unsigned lane = tid & 63u;
    const unsigned l15  = lane & 15u;
    const unsigned l4   = lane >> 4;         // 0..3

    // XCD-aware mapping (R4 win: FETCH 417->43 MB)
    const unsigned xcd = blockIdx.x & 7u;
    const unsigned loc = blockIdx.x >> 3;        // 0..63
    const unsigned b   = xcd * 4u + (loc >> 4);  // batch
    const unsigned qt  = loc & 15u;              // q-tile in batch
    const unsigned qbase = qt * QBLK;

    // staging maps (512 threads)
    const unsigned kr = tid >> 3, kc = tid & 7u;   // K: row 0..63, 32B chunk
    const unsigned vt = tid >> 4, vc = tid & 15u;  // V: key-pair 0..31, d-chunk

    // ---- Q -> A-fragments directly from global (scale folded in) ----
    s16x8 aq[2];
    {
        const float* qrow = qg + ((size_t)b * SQL + qbase + wid * 16 + l15) * DD;
        #pragma unroll
        for (int ks = 0; ks < 2; ++ks) {
            f32x4 f0 = *(const f32x4*)(qrow + ks * 32 + l4 * 8);
            f32x4 f1 = *(const f32x4*)(qrow + ks * 32 + l4 * 8 + 4);
            #pragma unroll
            for (int j = 0; j < 4; ++j) {
                aq[ks][j]     = (short)f2bf(f0[j] * 0.125f);
                aq[ks][j + 4] = (short)f2bf(f1[j] * 0.125f);
            }
        }
    }

    f32x4 acc_o[4];
    #pragma unroll
    for (int n = 0; n < 4; ++n) acc_o[n] = (f32x4){0.f, 0.f, 0.f, 0.f};

    const float* kbat = kg + (size_t)b * SKL * DD;
    const float* vbat = vg + (size_t)b * SKL * DD;

    auto stage = [&](int kt, int sel) {
        const float* ksrc = kbat + (size_t)kt * KBLK * DD;
        const float* vsrc = vbat + (size_t)kt * KBLK * DD;
        // K: 1 row x 32B fp32 per thread -> one b128 LDS write
        f32x4 k0 = *(const f32x4*)(ksrc + kr * DD + kc * 8);
        f32x4 k1 = *(const f32x4*)(ksrc + kr * DD + kc * 8 + 4);
        s16x8 h;
        #pragma unroll
        for (int j = 0; j < 4; ++j) {
            h[j]     = (short)f2bf(k0[j]);
            h[j + 4] = (short)f2bf(k1[j]);
        }
        *(s16x8*)(smem + KOFF + sel * 8192 + kr * 128 + ((kc * 16) ^ swzK(kr))) = h;
        // V^T: key-pair (2vt,2vt+1), d = vc*4..+3, packed 2 keys / u32
        f32x4 v0 = *(const f32x4*)(vsrc + (2 * vt) * DD + vc * 4);
        f32x4 v1 = *(const f32x4*)(vsrc + (2 * vt + 1) * DD + vc * 4);
        #pragma unroll
        for (int j = 0; j < 4; ++j) {
            unsigned d = vc * 4 + (unsigned)j;
            unsigned pack = (unsigned)f2bf(v0[j]) | ((unsigned)f2bf(v1[j]) << 16);
            *(unsigned*)(smem + VOFF + sel * 8192 + d * 128 + ((vt * 4) ^ swzV(d))) = pack;
        }
    };

    stage(0, 0);
    bar_lds();

    char* sbase = smem + SOFF + wid * 2048;   // wave-private S: 16 x 128 B
    const unsigned rr = lane >> 3, cc = lane & 7u;  // attn readback map

    for (int kt = 0; kt < NTILES; ++kt) {
        const int cur = kt & 1;
        if (kt + 1 < NTILES) stage(kt + 1, cur ^ 1);

        // ---- S = Q @ K^T : wave's 16 q-rows x 64 keys ----
        const char* kb = smem + KOFF + cur * 8192;
        f32x4 acc[4];
        #pragma unroll
        for (int n = 0; n < 4; ++n) acc[n] = (f32x4){0.f, 0.f, 0.f, 0.f};
        #pragma unroll
        for (int ks = 0; ks < 2; ++ks)
            #pragma unroll
            for (int nk = 0; nk < 4; ++nk) {
                unsigned row = nk * 16 + l15;
                s16x8 bk = *(const s16x8*)(kb + row * 128 +
                            ((ks * 64 + l4 * 16) ^ swzK(row)));
                acc[nk] = __builtin_amdgcn_mfma_f32_16x16x32_bf16(
                              aq[ks], bk, acc[nk], 0, 0, 0);
            }

        // ---- S -> wave-private LDS (bf16); same-wave ordering, no barrier ----
        #pragma unroll
        for (int nk = 0; nk < 4; ++nk)
            #pragma unroll
            for (int i = 0; i < 4; ++i) {
                unsigned q = l4 * 4 + (unsigned)i;
                unsigned key = nk * 16 + l15;
                *(unsigned short*)(sbase + q * 128 + ((key * 2) ^ swzS(q))) =
                    f2bf(acc[nk][i]);
            }

        // ---- attn stores via readback: 8 lanes/row -> 128B segments ----
        {
            float* abase = ag + ((size_t)b * SQL + qbase + wid * 16) * SKL
                              + (size_t)kt * KBLK;
            #pragma unroll
            for (int h = 0; h < 4; ++h) {
                unsigned q  = (h & 1) * 8 + rr;
                unsigned k4 = (h >> 1) * 32 + cc * 4;
                u32x2 p = *(const u32x2*)(sbase + q * 128 + ((k4 * 2) ^ swzS(q)));
                u32x4 w;
                w[0] = p[0] << 16; w[1] = p[0] & 0xFFFF0000u;
                w[2] = p[1] << 16; w[3] = p[1] & 0xFFFF0000u;
                __builtin_nontemporal_store(w,
                    (u32x4*)(abase + (size_t)q * SKL + k4));
            }
        }

        // ---- O += S @ V ----
        const char* vb = smem + VOFF + cur * 8192;
        #pragma unroll
        for (int ks = 0; ks < 2; ++ks) {
            s16x8 sa = *(const s16x8*)(sbase + l15 * 128 +
                        ((ks * 64 + l4 * 16) ^ swzS(l15)));
            #pragma unroll
            for (int nd = 0; nd < 4; ++nd) {
                unsigned row = nd * 16 + l15;
                s16x8 vf = *(const s16x8*)(vb + row * 128 +
                            ((ks * 64 + l4 * 16) ^ swzV(row)));
                acc_o[nd] = __builtin_amdgcn_mfma_f32_16x16x32_bf16(
                                sa, vf, acc_o[nd], 0, 0, 0);
            }
        }

        bar_lds();   // LDS-only barrier per tile (dbuf flip); stores uncounted
    }

    // ---- write O ----
    float* op = og + ((size_t)b * SQL + qbase + wid * 16 + l4 * 4) * DD + l15;
    #pragma unroll
    for (int nd = 0; nd < 4; ++nd)
        #pragma unroll
        for (int i = 0; i < 4; ++i)
            __builtin_nontemporal_store(acc_o[nd][i], op + (size_t)i * DD + nd * 16);
}

extern "C" void kernel_launch(void* const* d_in, const int* in_sizes, int n_in,
                              void* d_out, int out_size, void* d_ws, size_t ws_size,
                              hipStream_t stream) {
    const float* q = (const float*)d_in[0];
    const float* k = (const float*)d_in[1];
    const float* v = (const float*)d_in[2];
    float* outp  = (float*)d_out;                      // [32][2048][64]
    float* attnp = outp + (size_t)NB * SQL * DD;       // [32][2048][2048]
    sdpa_fused<<<dim3(NB * (SQL / QBLK)), dim3(512), 0, stream>>>(q, k, v, outp, attnp);
}